// Round 10
// baseline (1326.835 us; speedup 1.0000x reference)
//
#include <hip/hip_runtime.h>
#include <hip/hip_cooperative_groups.h>

namespace cg = cooperative_groups;

#define N_USERS 400000
#define N_ITEMS 200000
#define NNODES  600000   // N_USERS + N_ITEMS
#define D 64
#define B 8192
#define NB 1024          // mega-kernel blocks: 4/CU x 256 CU co-resident

// ---------------------------------------------------------------------------
// bf16 helpers
// ---------------------------------------------------------------------------
__device__ __forceinline__ float bflo(unsigned u) { return __uint_as_float(u << 16); }
__device__ __forceinline__ float bfhi(unsigned u) { return __uint_as_float(u & 0xffff0000u); }
__device__ __forceinline__ unsigned f2bf(float f) {   // round-to-nearest-even
    unsigned u = __float_as_uint(f);
    unsigned r = u + 0x7fffu + ((u >> 16) & 1u);
    return r >> 16;
}

__device__ __forceinline__ void unpack_fma(float* acc, uint4 wv, float v) {
    acc[0] += v * bflo(wv.x); acc[1] += v * bfhi(wv.x);
    acc[2] += v * bflo(wv.y); acc[3] += v * bfhi(wv.y);
    acc[4] += v * bflo(wv.z); acc[5] += v * bfhi(wv.z);
    acc[6] += v * bflo(wv.w); acc[7] += v * bfhi(wv.w);
}

// ---------------------------------------------------------------------------
// Cooperative mega-kernel: memset + hist + sizes | scan | scatter | marks
// Phases separated by grid.sync(); within a phase independent work overlaps.
// ---------------------------------------------------------------------------
__global__ __launch_bounds__(256, 4) void k_mega(
        const int* __restrict__ rows, const int* __restrict__ cols,
        const int* __restrict__ um, const int* __restrict__ im,
        const int* __restrict__ users, const int* __restrict__ pos,
        const int* __restrict__ neg,
        int* __restrict__ deg, int* __restrict__ row_ptr, int* __restrict__ nextp,
        int* __restrict__ sums, float* __restrict__ dinv, int* __restrict__ pcol,
        int* __restrict__ sizes, char* __restrict__ flag1, char* __restrict__ flag2,
        int nnz) {
    cg::grid_group grid = cg::this_grid();
    __shared__ int lds[256];
    __shared__ int carry;
    const int tid = blockIdx.x * 256 + threadIdx.x;
    const int gsz = NB * 256;

    // phase 0: zero deg + flags
    for (int i = tid; i < NNODES; i += gsz) { deg[i] = 0; flag1[i] = 0; flag2[i] = 0; }
    grid.sync();

    // phase 1: degree histogram (atomics) + mask sizes (streaming) — independent
    for (int e = tid; e < nnz; e += gsz) atomicAdd(&deg[rows[e]], 1);
    {
        const int nwaves = gsz / 64;
        const int wid = tid >> 6, lane = tid & 63;
        for (int r = wid; r < NNODES; r += nwaves) {
            int m = (r < N_USERS) ? um[(size_t)r * D + lane]
                                  : im[(size_t)(r - N_USERS) * D + lane];
            unsigned long long bal = __ballot(m != 0);
            if (lane == 0) sizes[r] = (int)__popcll(bal);
        }
    }
    grid.sync();

    // phase 2a: per-tile exclusive scan of deg (in place) + tile totals + dinv
    const int ntiles = (NNODES + 255) / 256;   // 2344
    for (int t = blockIdx.x; t < ntiles; t += NB) {
        int i = t * 256 + threadIdx.x;
        int v = (i < NNODES) ? deg[i] : 0;
        if (i < NNODES) dinv[i] = (v > 0) ? (float)(1.0 / sqrt((double)v)) : 0.0f;
        lds[threadIdx.x] = v;
        __syncthreads();
        for (int off = 1; off < 256; off <<= 1) {
            int t2 = (threadIdx.x >= off) ? lds[threadIdx.x - off] : 0;
            __syncthreads();
            lds[threadIdx.x] += t2;
            __syncthreads();
        }
        int inc = lds[threadIdx.x];
        if (i < NNODES) deg[i] = inc - v;
        if (threadIdx.x == 255) sums[t] = inc;
        __syncthreads();
    }
    grid.sync();

    // phase 2b: block 0 scans the tile totals (exclusive, with carry)
    if (blockIdx.x == 0) {
        if (threadIdx.x == 0) carry = 0;
        __syncthreads();
        for (int base = 0; base < ntiles; base += 256) {
            int i = base + threadIdx.x;
            int v = (i < ntiles) ? sums[i] : 0;
            lds[threadIdx.x] = v;
            __syncthreads();
            for (int off = 1; off < 256; off <<= 1) {
                int t2 = (threadIdx.x >= off) ? lds[threadIdx.x - off] : 0;
                __syncthreads();
                lds[threadIdx.x] += t2;
                __syncthreads();
            }
            int inc = lds[threadIdx.x];
            if (i < ntiles) sums[i] = (inc - v) + carry;
            __syncthreads();
            if (threadIdx.x == 255) carry += lds[255];
            __syncthreads();
        }
    }
    grid.sync();

    // phase 2c: fixup -> row_ptr, nextp
    for (int i = tid; i < NNODES; i += gsz) {
        int rp = deg[i] + sums[i >> 8];
        row_ptr[i] = rp;
        nextp[i] = rp;
    }
    if (tid == 0) row_ptr[NNODES] = nnz;
    grid.sync();

    // phase 3: scatter cols into CSR order
    for (int e = tid; e < nnz; e += gsz) {
        int r = rows[e];
        int p = atomicAdd(&nextp[r], 1);
        pcol[p] = cols[e];
    }
    grid.sync();

    // phase 4: mark samples + their 1-hop (flag2), samples into flag1
    for (int slot = tid; slot < 3 * B; slot += gsz) {
        int set = slot / B;
        int b = slot - set * B;
        int r;
        if (set == 0)      r = users[b];
        else if (set == 1) r = N_USERS + pos[b];
        else               r = N_USERS + neg[b];
        flag2[r] = 1;
        flag1[r] = 1;
        int e2 = row_ptr[r + 1];
        for (int i = row_ptr[r]; i < e2; ++i) flag2[pcol[i]] = 1;
    }
    grid.sync();

    // phase 5: flag1 = flag2 rows' neighbors (2-hop frontier for layer 1)
    for (int r = tid; r < NNODES; r += gsz) {
        if (!flag2[r]) continue;
        int e2 = row_ptr[r + 1];
        for (int i = row_ptr[r]; i < e2; ++i) flag1[pcol[i]] = 1;
    }
}

// ---------------------------------------------------------------------------
// Layer-1 SPMM from RAW f32 embeddings with inline prefix-mask (flag1 rows):
//   y1[r] = sum dinv[r]*dinv[c] * (emb[c] masked to sizes[c])
// 8 threads/row, 8 f32 cols each, bf16 output.
// ---------------------------------------------------------------------------
__global__ void k_spmm1(const int* __restrict__ row_ptr, const int* __restrict__ pcol,
                        const float* __restrict__ dinv, const int* __restrict__ sizes,
                        const char* __restrict__ flag1,
                        const float* __restrict__ ue, const float* __restrict__ ie,
                        unsigned* __restrict__ y1) {
    int tid = blockIdx.x * blockDim.x + threadIdx.x;
    int r = tid >> 3;
    if (r >= NNODES) return;
    if (!flag1[r]) return;
    int c8 = (tid & 7) << 3;
    int s = row_ptr[r];
    int e = row_ptr[r + 1];
    float dr = dinv[r];
    float acc[8] = {0.f, 0.f, 0.f, 0.f, 0.f, 0.f, 0.f, 0.f};
    for (int i = s; i < e; ++i) {
        int c = pcol[i];
        float v = dr * dinv[c];
        int sz = sizes[c];
        const float* p = ((c < N_USERS) ? ue + (size_t)c * D
                                        : ie + (size_t)(c - N_USERS) * D) + c8;
        float4 e0 = *(const float4*)p;
        float4 e1 = *(const float4*)(p + 4);
        acc[0] += v * ((c8 + 0 < sz) ? e0.x : 0.f);
        acc[1] += v * ((c8 + 1 < sz) ? e0.y : 0.f);
        acc[2] += v * ((c8 + 2 < sz) ? e0.z : 0.f);
        acc[3] += v * ((c8 + 3 < sz) ? e0.w : 0.f);
        acc[4] += v * ((c8 + 4 < sz) ? e1.x : 0.f);
        acc[5] += v * ((c8 + 5 < sz) ? e1.y : 0.f);
        acc[6] += v * ((c8 + 6 < sz) ? e1.z : 0.f);
        acc[7] += v * ((c8 + 7 < sz) ? e1.w : 0.f);
    }
    uint4 o;
    o.x = f2bf(acc[0]) | (f2bf(acc[1]) << 16);
    o.y = f2bf(acc[2]) | (f2bf(acc[3]) << 16);
    o.z = f2bf(acc[4]) | (f2bf(acc[5]) << 16);
    o.w = f2bf(acc[6]) | (f2bf(acc[7]) << 16);
    *(uint4*)(y1 + (size_t)r * 32 + (tid & 7) * 4) = o;
}

// ---------------------------------------------------------------------------
// Layer-2 bf16 SPMM, flag2 rows only: x2[r] = sum val * y1[col].
// ---------------------------------------------------------------------------
__global__ void k_spmm2(const int* __restrict__ row_ptr, const int* __restrict__ pcol,
                        const float* __restrict__ dinv, const char* __restrict__ flag2,
                        const unsigned* __restrict__ y1, unsigned* __restrict__ x2) {
    int tid = blockIdx.x * blockDim.x + threadIdx.x;
    int r = tid >> 3;
    if (r >= NNODES) return;
    if (!flag2[r]) return;
    int cp = (tid & 7) << 2;
    int s = row_ptr[r];
    int e = row_ptr[r + 1];
    float dr = dinv[r];
    float acc[8] = {0.f, 0.f, 0.f, 0.f, 0.f, 0.f, 0.f, 0.f};
    int i = s;
    for (; i + 1 < e; i += 2) {
        int c0 = pcol[i], c1 = pcol[i + 1];
        float v0 = dr * dinv[c0], v1 = dr * dinv[c1];
        uint4 w0 = *(const uint4*)(y1 + (size_t)c0 * 32 + cp);
        uint4 w1 = *(const uint4*)(y1 + (size_t)c1 * 32 + cp);
        unpack_fma(acc, w0, v0);
        unpack_fma(acc, w1, v1);
    }
    if (i < e) {
        int c0 = pcol[i];
        float v0 = dr * dinv[c0];
        uint4 w0 = *(const uint4*)(y1 + (size_t)c0 * 32 + cp);
        unpack_fma(acc, w0, v0);
    }
    uint4 o;
    o.x = f2bf(acc[0]) | (f2bf(acc[1]) << 16);
    o.y = f2bf(acc[2]) | (f2bf(acc[3]) << 16);
    o.z = f2bf(acc[4]) | (f2bf(acc[5]) << 16);
    o.w = f2bf(acc[6]) | (f2bf(acc[7]) << 16);
    *(uint4*)(x2 + (size_t)r * 32 + cp) = o;
}

// ---------------------------------------------------------------------------
// Final sampled layer, fully fused:
//   x0r = masked f32 emb row (exact)
//   out[slot]      = (x0r + y1[r] + x2[r] + sum val * x2[col]) * 0.25
//   out[3B + slot] = x0r (ego)
// ---------------------------------------------------------------------------
__global__ void k_spmm3(const int* __restrict__ row_ptr, const int* __restrict__ pcol,
                        const float* __restrict__ dinv, const int* __restrict__ sizes,
                        const float* __restrict__ ue, const float* __restrict__ ie,
                        const unsigned* __restrict__ y1, const unsigned* __restrict__ x2,
                        const int* __restrict__ users, const int* __restrict__ pos,
                        const int* __restrict__ neg, float* __restrict__ out) {
    int tid = blockIdx.x * blockDim.x + threadIdx.x;
    int slot = tid >> 3;
    if (slot >= 3 * B) return;
    int cp = (tid & 7) << 2;
    int c8 = (tid & 7) << 3;
    int set = slot / B;
    int b = slot - set * B;
    int r;
    if (set == 0)      r = users[b];
    else if (set == 1) r = N_USERS + pos[b];
    else               r = N_USERS + neg[b];
    int s = row_ptr[r];
    int e = row_ptr[r + 1];
    float dr = dinv[r];
    float acc[8] = {0.f, 0.f, 0.f, 0.f, 0.f, 0.f, 0.f, 0.f};
    uint4 g1 = *(const uint4*)(y1 + (size_t)r * 32 + cp);
    uint4 g2 = *(const uint4*)(x2 + (size_t)r * 32 + cp);
    unpack_fma(acc, g1, 1.0f);
    unpack_fma(acc, g2, 1.0f);
    int i = s;
    for (; i + 1 < e; i += 2) {
        int c0 = pcol[i], c1 = pcol[i + 1];
        float v0 = dr * dinv[c0], v1 = dr * dinv[c1];
        uint4 w0 = *(const uint4*)(x2 + (size_t)c0 * 32 + cp);
        uint4 w1 = *(const uint4*)(x2 + (size_t)c1 * 32 + cp);
        unpack_fma(acc, w0, v0);
        unpack_fma(acc, w1, v1);
    }
    if (i < e) {
        int c0 = pcol[i];
        float v0 = dr * dinv[c0];
        uint4 w0 = *(const uint4*)(x2 + (size_t)c0 * 32 + cp);
        unpack_fma(acc, w0, v0);
    }
    const float* p = ((r < N_USERS) ? ue + (size_t)r * D
                                    : ie + (size_t)(r - N_USERS) * D) + c8;
    float4 e0 = *(const float4*)p;
    float4 e1 = *(const float4*)(p + 4);
    int sz = sizes[r];
    e0.x = (c8 + 0 < sz) ? e0.x : 0.f; e0.y = (c8 + 1 < sz) ? e0.y : 0.f;
    e0.z = (c8 + 2 < sz) ? e0.z : 0.f; e0.w = (c8 + 3 < sz) ? e0.w : 0.f;
    e1.x = (c8 + 4 < sz) ? e1.x : 0.f; e1.y = (c8 + 5 < sz) ? e1.y : 0.f;
    e1.z = (c8 + 6 < sz) ? e1.z : 0.f; e1.w = (c8 + 7 < sz) ? e1.w : 0.f;
    float4 oa, ob;
    oa.x = (e0.x + acc[0]) * 0.25f; oa.y = (e0.y + acc[1]) * 0.25f;
    oa.z = (e0.z + acc[2]) * 0.25f; oa.w = (e0.w + acc[3]) * 0.25f;
    ob.x = (e1.x + acc[4]) * 0.25f; ob.y = (e1.y + acc[5]) * 0.25f;
    ob.z = (e1.z + acc[6]) * 0.25f; ob.w = (e1.w + acc[7]) * 0.25f;
    float* o0 = out + (size_t)slot * D + c8;
    float* o1 = out + (size_t)(3 * B + slot) * D + c8;
    *(float4*)o0 = oa; *(float4*)(o0 + 4) = ob;
    *(float4*)o1 = e0; *(float4*)(o1 + 4) = e1;
}

extern "C" void kernel_launch(void* const* d_in, const int* in_sizes, int n_in,
                              void* d_out, int out_size, void* d_ws, size_t ws_size,
                              hipStream_t stream) {
    const int*   rows = (const int*)d_in[4];
    const int*   cols = (const int*)d_in[5];
    const float* ue   = (const float*)d_in[0];
    const float* ie   = (const float*)d_in[1];
    const int*   um   = (const int*)d_in[2];
    const int*   im   = (const int*)d_in[3];
    const int*   users = (const int*)d_in[7];
    const int*   pos   = (const int*)d_in[8];
    const int*   neg   = (const int*)d_in[9];
    int nnz = in_sizes[4];

    float* out = (float*)d_out;

    // workspace layout (16B-aligned bf16 node buffers first)
    unsigned short* Y1 = (unsigned short*)d_ws;         // NNODES*D bf16
    unsigned short* X2 = Y1 + (size_t)NNODES * D;       // NNODES*D bf16
    int*   deg     = (int*)(X2 + (size_t)NNODES * D);   // NNODES
    int*   row_ptr = deg + NNODES;                      // NNODES+1
    int*   nextp   = row_ptr + NNODES + 1;              // NNODES
    int*   sizes   = nextp + NNODES;                    // NNODES
    int*   sums    = sizes + NNODES;                    // up to 4096
    float* dinv    = (float*)(sums + 4096);             // NNODES
    int*   pcol    = (int*)(dinv + NNODES);             // nnz
    char*  flag1   = (char*)(pcol + nnz);               // NNODES
    char*  flag2   = flag1 + NNODES;                    // NNODES

    const int blk = 256;

    // --- cooperative mega-kernel: memset+hist+sizes | scan | scatter | marks ---
    {
        void* args[] = {
            (void*)&rows, (void*)&cols, (void*)&um, (void*)&im,
            (void*)&users, (void*)&pos, (void*)&neg,
            (void*)&deg, (void*)&row_ptr, (void*)&nextp,
            (void*)&sums, (void*)&dinv, (void*)&pcol,
            (void*)&sizes, (void*)&flag1, (void*)&flag2, (void*)&nnz
        };
        hipLaunchCooperativeKernel((void*)k_mega, dim3(NB), dim3(256), args, 0, stream);
    }

    int n_full = NNODES * 8;
    int n_samp = 3 * B * 8;

    // layer 1 (flag1 rows): Y1 = A * masked_emb
    k_spmm1<<<(n_full + blk - 1) / blk, blk, 0, stream>>>(row_ptr, pcol, dinv, sizes, flag1,
                                                          ue, ie, (unsigned*)Y1);

    // layer 2 (flag2 rows): X2 = A * Y1
    k_spmm2<<<(n_full + blk - 1) / blk, blk, 0, stream>>>(row_ptr, pcol, dinv, flag2,
                                                          (const unsigned*)Y1, (unsigned*)X2);

    // layer 3: sampled rows, fully fused epilogue + ego
    k_spmm3<<<(n_samp + blk - 1) / blk, blk, 0, stream>>>(row_ptr, pcol, dinv, sizes,
                                                          ue, ie,
                                                          (const unsigned*)Y1,
                                                          (const unsigned*)X2,
                                                          users, pos, neg, out);
}